// Round 6
// baseline (1696.860 us; speedup 1.0000x reference)
//
#include <hip/hip_runtime.h>

// Q4_0 quantized linear: out[16, 11008] = x[16, 4096] @ ((w_q-8)*w_scale).T + bias
// All fp32; w_q holds int32 nibble values in [0,16).
//
// R6: R5's direct-to-LDS structure with the spill fixed.
// Empirical hipcc rule (4 data points this session): __launch_bounds__(256,N)
// caps VGPR at ~256/N and the allocator SPILLS to meet it:
//   N=4 -> 64  (R3, R5: acc[16] spilled -> GBs of scratch traffic, ~1.5 ms)
//   N=3 -> 85  (R4: R0's 84-reg body just fit)
//   no N -> 256 allowed (R2: compiler ballooned a prefetch pipeline)
// This body needs ~65-100 VGPR -> use N=2 (cap 128): no spill, still
// 4 waves/SIMD; LDS 40 KiB already caps residency at 4 blocks/CU.
//
// Structure (R5, correctness-proven): each weight row is consumed by exactly
// ONE thread -- the LDS w-tile is purely a coalescing reshaper, so stage RAW
// int32 via __builtin_amdgcn_global_load_lds (16 B/lane, 8 fire-and-forget
// 1-KB wave-instrs per sub = Little's-law-deep, zero staging VGPRs, zero
// pack VALU). ws row = 128 B would be a 32-way ds_read_b128 conflict; the
// 16-B chunk index is XOR-swizzled with (row&7) on the PER-LANE GLOBAL
// source address (LDS dest stays linear, as global_load_lds requires) and
// mirrored on the read -> uniform 32 B/bank = structural floor.
// Floors: w-stream 180 MB @ 6.3 TB/s ~= 29 us; FMA ~10 us; LDS ~5 us.

constexpr int T       = 16;
constexpr int IN      = 4096;
constexpr int OUT     = 11008;
constexpr int NSCALE  = IN / 32;        // 128 scales per row
constexpr int THREADS = 256;
constexpr int ROWSB   = THREADS;        // 1 row per thread; 11008 = 43*256 exact
constexpr int CK      = 128;            // k per block -> 32 k-splits
constexpr int WSUB    = 32;             // k per stage (== Q4_0 block size)
constexpr int NSUB    = CK / WSUB;      // 4
constexpr int XPAD    = 16;             // xs row stride floats (64 B; keeps LDS at 40 KiB -> 4 blocks/CU)

__device__ __forceinline__ void gload_lds16(const int* g, int* l) {
    // 16 B per lane, global (per-lane addr) -> LDS (wave-uniform base + lane*16)
    __builtin_amdgcn_global_load_lds(
        (const __attribute__((address_space(1))) void*)g,
        (__attribute__((address_space(3))) void*)l,
        16, 0, 0);
}

__global__ __launch_bounds__(THREADS, 2) void qlinear_dlds2(
    const float* __restrict__ x,        // [T, IN]
    const int*   __restrict__ w_q,      // [OUT, IN]
    const float* __restrict__ w_scale,  // [OUT, NSCALE]
    const float* __restrict__ bias,     // [OUT]
    float* __restrict__ out)            // [T, OUT] (pre-zeroed)
{
    __shared__ __align__(16) float xs[CK][XPAD];      // 8 KiB
    __shared__ __align__(16) int   ws[ROWSB * WSUB];  // 32 KiB raw int32 weights

    const int tid  = threadIdx.x;
    const int row0 = blockIdx.x * ROWSB;
    const int k0   = blockIdx.y * CK;
    const int row  = row0 + tid;        // < OUT always (exact tiling)

    // ---- stage x chunk transposed: xs[k][t] = x[t][k0+k] (coalesced) ----
    #pragma unroll
    for (int it = 0; it < CK * T / THREADS; ++it) {  // 8
        int idx = it * THREADS + tid;
        int t   = idx >> 7;          // idx / CK
        int k   = idx & (CK - 1);
        xs[k][t] = x[t * IN + k0 + k];
    }

    // ---- per-row scales for the 4 sub-blocks of this k-chunk ----
    const float4 sc = *(const float4*)(w_scale + row * NSCALE + (k0 >> 5));

    // ---- staging geometry ----
    // One wave-instr moves 8 rows x 128 B. lane l: r8 = l>>3 (row within
    // group), c = l&7 (16-B slot). Slot (r8,c) receives global chunk c^r8,
    // so reading row r chunk j uses LDS chunk j^(r&7)  (r8 == row&7 since
    // groups are 8-aligned).
    const int lane_r8 = (tid >> 3) & 7;
    const int lane_c  = tid & 7;
    const int phys_c  = lane_c ^ lane_r8;   // swizzled global chunk index
    const int wrow0   = tid & ~63;          // wave's first row in the block

    auto stage_w = [&](int s) {
        #pragma unroll
        for (int i = 0; i < 8; ++i) {       // 8 x 1 KB per wave, fire-and-forget
            const int  r = wrow0 + i * 8 + lane_r8;
            const int* g = w_q + (size_t)(row0 + r) * IN + (k0 + s * WSUB + phys_c * 4);
            int*       l = ws + (wrow0 + i * 8) * WSUB;   // wave-uniform base
            gload_lds16(g, l);
        }
    };

    float acc[T];
    #pragma unroll
    for (int t = 0; t < T; ++t) acc[t] = 0.0f;

    stage_w(0);
    __syncthreads();    // drains lgkm (xs writes) + vmcnt (ws sub-0 loads)

    #pragma unroll
    for (int sub = 0; sub < NSUB; ++sub) {           // 4
        const float s  = (sub == 0) ? sc.x : (sub == 1) ? sc.y
                       : (sub == 2) ? sc.z : sc.w;   // sub is constant
        const float s8 = -8.0f * s;                  // exact

        for (int k4 = 0; k4 < WSUB / 4; ++k4) {      // 8 (rolled)
            // own row, swizzled chunk: uniform 32 B/bank = structural floor
            const int4 qv = *(const int4*)(ws + tid * WSUB + ((k4 ^ (tid & 7)) << 2));

            #pragma unroll
            for (int kk = 0; kk < 4; ++kk) {
                const int qq = (kk == 0) ? qv.x : (kk == 1) ? qv.y
                             : (kk == 2) ? qv.z : qv.w;
                // (q - 8) * s with a single rounding; v_cvt_f32_i32 + fma
                const float wv = fmaf((float)qq, s, s8);
                const float4* xp = (const float4*)&xs[sub * WSUB + k4 * 4 + kk][0];
                const float4 x0 = xp[0], x1 = xp[1], x2 = xp[2], x3 = xp[3];
                acc[0]  = fmaf(wv, x0.x, acc[0]);
                acc[1]  = fmaf(wv, x0.y, acc[1]);
                acc[2]  = fmaf(wv, x0.z, acc[2]);
                acc[3]  = fmaf(wv, x0.w, acc[3]);
                acc[4]  = fmaf(wv, x1.x, acc[4]);
                acc[5]  = fmaf(wv, x1.y, acc[5]);
                acc[6]  = fmaf(wv, x1.z, acc[6]);
                acc[7]  = fmaf(wv, x1.w, acc[7]);
                acc[8]  = fmaf(wv, x2.x, acc[8]);
                acc[9]  = fmaf(wv, x2.y, acc[9]);
                acc[10] = fmaf(wv, x2.z, acc[10]);
                acc[11] = fmaf(wv, x2.w, acc[11]);
                acc[12] = fmaf(wv, x3.x, acc[12]);
                acc[13] = fmaf(wv, x3.y, acc[13]);
                acc[14] = fmaf(wv, x3.z, acc[14]);
                acc[15] = fmaf(wv, x3.w, acc[15]);
            }
        }

        if (sub + 1 < NSUB) {
            __syncthreads();        // all waves done reading ws
            stage_w(sub + 1);
            __syncthreads();        // loads landed (barrier drains vmcnt);
                                    // cross-block overlap (4/CU) hides this
        }
    }

    // ---- epilogue: bias (split 0 only) + atomic combine across splits ----
    const float b = (blockIdx.y == 0) ? bias[row] : 0.0f;
    #pragma unroll
    for (int t = 0; t < T; ++t)
        atomicAdd(out + t * OUT + row, acc[t] + b);
}

extern "C" void kernel_launch(void* const* d_in, const int* in_sizes, int n_in,
                              void* d_out, int out_size, void* d_ws, size_t ws_size,
                              hipStream_t stream) {
    const float* x       = (const float*)d_in[0];
    const int*   w_q     = (const int*)d_in[1];
    const float* w_scale = (const float*)d_in[2];
    const float* bias    = (const float*)d_in[3];
    float*       out     = (float*)d_out;

    // Zero the (0xAA-poisoned) output; captured as a graph memset node.
    hipMemsetAsync(d_out, 0, (size_t)out_size * sizeof(float), stream);

    dim3 grid(OUT / ROWSB, IN / CK);   // 43 x 32 = 1376 blocks
    qlinear_dlds2<<<grid, THREADS, 0, stream>>>(x, w_q, w_scale, bias, out);
}

// Round 7
// 281.685 us; speedup vs baseline: 6.0240x; 6.0240x over previous
//
#include <hip/hip_runtime.h>

// Q4_0 quantized linear: out[16, 11008] = x[16, 4096] @ ((w_q-8)*w_scale).T + bias
// All fp32; w_q holds int32 nibble values in [0,16).
//
// R7: LDS-free weight streaming.
// Chain of evidence:
//  R0/R4: coalesced reg->LDS staging, only 4 KB/wave in flight -> latency-
//         bound ~105-110 us regardless of occupancy (R4: 2x blocks, no gain).
//  R1/R2/R3: deeper reg staging variants -> register allocator blowups.
//  R5/R6: global_load_lds with per-lane SCATTERED source (8 rows 16 KB
//         apart per wave-instr): DMA path does not coalesce across rows ->
//         every 16-B lane request pulled a 128-B line (FETCH 1.48 GB = 8x
//         the 180 MB w-stream), 4.3 GB fabric storm, 1.5 ms. The guide's
//         working global_load_lds pattern is a CONTIGUOUS 1-KB/wave span;
//         this tile shape can't provide one.
// Fix: each weight row is consumed by exactly ONE thread, so drop the
// w-LDS tile entirely. Thread t streams its own row: per sub, 8x
// global_load_dwordx4 over one 128-B-aligned span. Lanes are uncoalesced
// across rows, but each lane's 8 chunk reads hit the SAME 128-B line
// (MSHR-merged) -> zero overfetch (~210 MB total). TA rate: 11.25M
// lane-requests / 256 CU ~= 18 us < 29 us HBM floor. In flight: 16
// waves/CU x 8 KB = 128 KB/CU (Little's law satisfied). No barriers in
// the k-loop; LDS = 10 KB broadcast x tile only.
// Register control (the session's recurring failure mode):
//  - acc[16] (R=1) + v[8] int4 (32) + temps ~= 90 VGPR.
//  - __launch_bounds__(256,2): cap 128 -- generous, blocks the R2 balloon.
//  - #pragma unroll 1 on the sub loop: forbids hoisting all 32 int4 loads.
// Floors: w-stream 180 MB @ 6.3 TB/s ~= 29 us; FMA ~10 us.

constexpr int T       = 16;
constexpr int IN      = 4096;
constexpr int OUT     = 11008;
constexpr int NSCALE  = IN / 32;        // 128 scales per row
constexpr int THREADS = 256;
constexpr int ROWSB   = THREADS;        // 1 row per thread; 11008 = 43*256 exact
constexpr int CK      = 128;            // k per block -> 32 k-splits
constexpr int WSUB    = 32;             // k per stage (== Q4_0 block size)
constexpr int NSUB    = CK / WSUB;      // 4
constexpr int XPAD    = 20;             // xs row stride floats (80 B, 16-B aligned,
                                        // 8-bank spread on the staging writes)

__global__ __launch_bounds__(THREADS, 2) void qlinear_rowstream(
    const float* __restrict__ x,        // [T, IN]
    const int*   __restrict__ w_q,      // [OUT, IN]
    const float* __restrict__ w_scale,  // [OUT, NSCALE]
    const float* __restrict__ bias,     // [OUT]
    float* __restrict__ out)            // [T, OUT] (pre-zeroed)
{
    __shared__ __align__(16) float xs[CK][XPAD];     // 10 KiB; only LDS use

    const int tid  = threadIdx.x;
    const int row0 = blockIdx.x * ROWSB;
    const int k0   = blockIdx.y * CK;
    const int row  = row0 + tid;        // < OUT always (exact tiling)

    // ---- stage x chunk transposed: xs[k][t] = x[t][k0+k] (coalesced) ----
    #pragma unroll
    for (int it = 0; it < CK * T / THREADS; ++it) {  // 8
        int idx = it * THREADS + tid;
        int t   = idx >> 7;          // idx / CK
        int k   = idx & (CK - 1);
        xs[k][t] = x[t * IN + k0 + k];
    }

    // ---- per-row scales for the 4 sub-blocks of this k-chunk ----
    const float4 sc = *(const float4*)(w_scale + row * NSCALE + (k0 >> 5));

    // thread-private row pointer (512 B span for this k-chunk, 16-B aligned)
    const int* wp = w_q + (size_t)row * IN + k0;

    float acc[T];
    #pragma unroll
    for (int t = 0; t < T; ++t) acc[t] = 0.0f;

    __syncthreads();    // xs visible to all waves (only barrier in the kernel)

    #pragma unroll 1    // do NOT unroll: prevents hoisting all 32 int4 loads
    for (int sub = 0; sub < NSUB; ++sub) {           // 4
        // ---- issue this sub's 8 chunk loads; 7/8 are same-line hits ----
        int4 v[8];
        #pragma unroll
        for (int j = 0; j < 8; ++j)
            v[j] = *(const int4*)(wp + sub * WSUB + j * 4);

        const float s  = (sub == 0) ? sc.x : (sub == 1) ? sc.y
                       : (sub == 2) ? sc.z : sc.w;
        const float s8 = -8.0f * s;                  // exact

        #pragma unroll
        for (int k4 = 0; k4 < WSUB / 4; ++k4) {      // 8
            const int4 qv = v[k4];
            #pragma unroll
            for (int kk = 0; kk < 4; ++kk) {
                const int qq = (kk == 0) ? qv.x : (kk == 1) ? qv.y
                             : (kk == 2) ? qv.z : qv.w;
                // (q - 8) * s with a single rounding; v_cvt_f32_i32 + fma
                const float wv = fmaf((float)qq, s, s8);
                // broadcast read: all lanes same address -> no bank conflict
                const float4* xp = (const float4*)&xs[sub * WSUB + k4 * 4 + kk][0];
                const float4 x0 = xp[0], x1 = xp[1], x2 = xp[2], x3 = xp[3];
                acc[0]  = fmaf(wv, x0.x, acc[0]);
                acc[1]  = fmaf(wv, x0.y, acc[1]);
                acc[2]  = fmaf(wv, x0.z, acc[2]);
                acc[3]  = fmaf(wv, x0.w, acc[3]);
                acc[4]  = fmaf(wv, x1.x, acc[4]);
                acc[5]  = fmaf(wv, x1.y, acc[5]);
                acc[6]  = fmaf(wv, x1.z, acc[6]);
                acc[7]  = fmaf(wv, x1.w, acc[7]);
                acc[8]  = fmaf(wv, x2.x, acc[8]);
                acc[9]  = fmaf(wv, x2.y, acc[9]);
                acc[10] = fmaf(wv, x2.z, acc[10]);
                acc[11] = fmaf(wv, x2.w, acc[11]);
                acc[12] = fmaf(wv, x3.x, acc[12]);
                acc[13] = fmaf(wv, x3.y, acc[13]);
                acc[14] = fmaf(wv, x3.z, acc[14]);
                acc[15] = fmaf(wv, x3.w, acc[15]);
            }
        }
    }

    // ---- epilogue: bias (split 0 only) + atomic combine across splits ----
    const float b = (blockIdx.y == 0) ? bias[row] : 0.0f;
    #pragma unroll
    for (int t = 0; t < T; ++t)
        atomicAdd(out + t * OUT + row, acc[t] + b);   // consecutive rows/lane
}

extern "C" void kernel_launch(void* const* d_in, const int* in_sizes, int n_in,
                              void* d_out, int out_size, void* d_ws, size_t ws_size,
                              hipStream_t stream) {
    const float* x       = (const float*)d_in[0];
    const int*   w_q     = (const int*)d_in[1];
    const float* w_scale = (const float*)d_in[2];
    const float* bias    = (const float*)d_in[3];
    float*       out     = (float*)d_out;

    // Zero the (0xAA-poisoned) output; captured as a graph memset node.
    hipMemsetAsync(d_out, 0, (size_t)out_size * sizeof(float), stream);

    dim3 grid(OUT / ROWSB, IN / CK);   // 43 x 32 = 1376 blocks
    qlinear_rowstream<<<grid, THREADS, 0, stream>>>(x, w_q, w_scale, bias, out);
}